// Round 1
// 465.513 us; speedup vs baseline: 1.1655x; 1.1655x over previous
//
#include <hip/hip_runtime.h>
#include <hip/hip_bf16.h>

#define NROWS 32768
#define DIM   512
#define HEADS 8
#define LN_EPS 1e-5f

typedef __attribute__((ext_vector_type(8))) short short8;   // 8 bf16 (4 VGPRs)
typedef __attribute__((ext_vector_type(4))) float floatx4;  // MFMA acc

typedef __attribute__((address_space(3))) void lds_void;
typedef __attribute__((address_space(1))) void gbl_void;

// async global->LDS, 16 B per lane; LDS dest = wave-uniform base + lane*16
__device__ __forceinline__ void async16(const void* g, void* l) {
    __builtin_amdgcn_global_load_lds(
        (gbl_void*)(unsigned long long)(uintptr_t)g,
        (lds_void*)(unsigned int)(uintptr_t)l,
        16, 0, 0);
}

// ---------------------------------------------------------------------------
// h (fp32) -> hb (bf16), vectorized
// ---------------------------------------------------------------------------
__global__ __launch_bounds__(256) void hconv_kernel(
    const float* __restrict__ h, __hip_bfloat16* __restrict__ hb)
{
    const size_t i = ((size_t)blockIdx.x * 256 + threadIdx.x) * 4;
    const float4 f = *(const float4*)(h + i);
    union { ushort4 u; __hip_bfloat16 b[4]; } pk;
    pk.b[0] = __float2bfloat16(f.x);
    pk.b[1] = __float2bfloat16(f.y);
    pk.b[2] = __float2bfloat16(f.z);
    pk.b[3] = __float2bfloat16(f.w);
    *(ushort4*)(hb + i) = pk.u;
}

// ---------------------------------------------------------------------------
// All four W [K=512][N=512] fp32 -> Wt [N][K] bf16, one launch (blockIdx.z).
// wtq/wtk/wtv land contiguous -> QKV GEMM sees one 1536x512 Bt.
// ---------------------------------------------------------------------------
__global__ __launch_bounds__(256) void wtrans_kernel(
    const float* __restrict__ Wq, const float* __restrict__ Wk,
    const float* __restrict__ Wv, const float* __restrict__ Wf,
    __hip_bfloat16* __restrict__ Wt)
{
    __shared__ float tile[32][33];
    const int z = blockIdx.z;
    const float* W = (z == 0) ? Wq : (z == 1) ? Wk : (z == 2) ? Wv : Wf;
    __hip_bfloat16* dst = Wt + (size_t)z * DIM * DIM;

    const int bn = blockIdx.x * 32;   // n block
    const int bk = blockIdx.y * 32;   // k block
    const int tx = threadIdx.x & 31;
    const int ty = threadIdx.x >> 5;  // 0..7
    #pragma unroll
    for (int i = ty; i < 32; i += 8)
        tile[i][tx] = W[(size_t)(bk + i) * DIM + bn + tx];
    __syncthreads();
    #pragma unroll
    for (int i = ty; i < 32; i += 8)
        dst[(size_t)(bn + i) * DIM + bk + tx] = __float2bfloat16(tile[tx][i]);
}

// ---------------------------------------------------------------------------
// MFMA GEMM: C[M,*] fp32 = A[M,512](bf16) @ Bt[n][k](bf16)^T.
// 128x128 tile, BK=64 (8 k-iters of 32 MFMA/wave), 256 thr = 4 waves (2x2).
// LDS: row r holds 8 chunks of 16B, physical chunk = r*8 + (c ^ (r&7))
// (G4 XOR swizzle -> frag ds_read_b128 conflict-free; realized by
//  pre-swizzling the per-lane GLOBAL source, LDS dest stays linear [m173]).
// qkv mode: Bt is the 1536-row concat; C panel = bx>>2 (stride NROWS*DIM),
// col = (bx&3)*128, relu on q,k only.
// ---------------------------------------------------------------------------
__global__ __launch_bounds__(256) void mfma_gemm_kernel(
    const __hip_bfloat16* __restrict__ A,
    const __hip_bfloat16* __restrict__ Bt,
    float* __restrict__ C, int qkv)
{
    __shared__ __align__(16) char smem[32768];   // As 16 KB | Bs 16 KB

    const int t    = threadIdx.x;
    const int lane = t & 63;
    const int w    = t >> 6;
    const int wm   = w >> 1, wn = w & 1;
    const int l16  = lane & 15, quad = lane >> 4;
    const int bm   = blockIdx.y * 128;
    const int bx   = blockIdx.x;
    const int bn   = bx * 128;          // Bt row panel (global across concat)

    float* Cp;
    int ccol, relu;
    if (qkv) {
        Cp   = C + (size_t)(bx >> 2) * ((size_t)NROWS * DIM);
        ccol = (bx & 3) * 128;
        relu = (bx >> 2) < 2;
    } else {
        Cp = C; ccol = bn; relu = 0;
    }

    // staging: tile = 128 rows x 8 chunks(16B) = 1024 chunks.
    // wave w call s covers physical chunks p = w*256 + s*64 + lane.
    int offA[4], offB[4];
    char* dA[4]; char* dB[4];
    #pragma unroll
    for (int s = 0; s < 4; ++s) {
        const int p = w * 256 + s * 64 + lane;
        const int r = p >> 3;
        const int c = (p & 7) ^ (r & 7);     // logical k-chunk stored here
        offA[s] = (bm + r) * DIM + c * 8;
        offB[s] = (bn + r) * DIM + c * 8;
        dA[s] = smem + (w * 256 + s * 64) * 16;
        dB[s] = smem + 16384 + (w * 256 + s * 64) * 16;
    }

    // loop-invariant frag LDS byte offsets (kk = which K=32 half)
    int aoff[2][4], boff[2][4];
    #pragma unroll
    for (int kk = 0; kk < 2; ++kk)
        #pragma unroll
        for (int i = 0; i < 4; ++i) {
            const int ra = wm * 64 + i * 16 + l16;
            aoff[kk][i] = (ra * 8 + ((kk * 4 + quad) ^ (ra & 7))) * 16;
            const int rb = wn * 64 + i * 16 + l16;
            boff[kk][i] = 16384 + (rb * 8 + ((kk * 4 + quad) ^ (rb & 7))) * 16;
        }

    floatx4 acc[4][4];
    #pragma unroll
    for (int i = 0; i < 4; ++i)
        #pragma unroll
        for (int j = 0; j < 4; ++j)
            acc[i][j] = (floatx4){0.f, 0.f, 0.f, 0.f};

    for (int k0 = 0; k0 < DIM; k0 += 64) {
        #pragma unroll
        for (int s = 0; s < 4; ++s) async16(A + offA[s] + k0, dA[s]);
        #pragma unroll
        for (int s = 0; s < 4; ++s) async16(Bt + offB[s] + k0, dB[s]);
        __syncthreads();   // drains vmcnt incl. global_load_lds

        #pragma unroll
        for (int kk = 0; kk < 2; ++kk) {
            short8 af[4], bf[4];
            #pragma unroll
            for (int i = 0; i < 4; ++i) af[i] = *(const short8*)(smem + aoff[kk][i]);
            #pragma unroll
            for (int j = 0; j < 4; ++j) bf[j] = *(const short8*)(smem + boff[kk][j]);
            #pragma unroll
            for (int i = 0; i < 4; ++i)
                #pragma unroll
                for (int j = 0; j < 4; ++j)
                    acc[i][j] = __builtin_amdgcn_mfma_f32_16x16x32_bf16(
                        af[i], bf[j], acc[i][j], 0, 0, 0);
        }

        __syncthreads();   // LDS reuse next iter
    }

    // epilogue: D row = quad*4 + reg, col = lane&15  [m89]
    #pragma unroll
    for (int i = 0; i < 4; ++i) {
        const int gr = bm + wm * 64 + i * 16 + quad * 4;
        #pragma unroll
        for (int j = 0; j < 4; ++j) {
            const int gc = ccol + wn * 64 + j * 16 + l16;
            #pragma unroll
            for (int rg = 0; rg < 4; ++rg) {
                float vv = acc[i][j][rg];
                if (relu) vv = fmaxf(vv, 0.f);
                Cp[(size_t)(gr + rg) * DIM + gc] = vv;
            }
        }
    }
}

// ---------------------------------------------------------------------------
// Linear attention, S-form:  num = (q k^T) v,  denom = rowsum(q k^T).
// Per row: S is only 8x8 (H=8) -> 16 KFLOP/row vs 131 K for the kv-form.
// One wave per row, 4 rows/block. Single barrier; P broadcast via shfl.
// Writes attn directly as bf16 (input to the Wf GEMM).
// ---------------------------------------------------------------------------
__global__ __launch_bounds__(256) void attn_kernel(
    const float* __restrict__ q, const float* __restrict__ k,
    const float* __restrict__ v, __hip_bfloat16* __restrict__ attn)
{
    __shared__ float sq[4][8][68];   // [wave][head][64, pad 68 keeps 16B align]
    __shared__ float sk[4][8][68];
    __shared__ float sv[4][8][68];

    const int t = threadIdx.x;
    const int w = t >> 6, lane = t & 63;
    const size_t base = ((size_t)blockIdx.x * 4 + w) * DIM;

    // stage one row of q,k,v: lane covers 8 floats (head sh, offset sd)
    const int sh = lane >> 3;
    const int sd = (lane & 7) * 8;
    {
        const float4 q0 = ((const float4*)(q + base))[lane * 2];
        const float4 q1 = ((const float4*)(q + base))[lane * 2 + 1];
        const float4 k0 = ((const float4*)(k + base))[lane * 2];
        const float4 k1 = ((const float4*)(k + base))[lane * 2 + 1];
        const float4 v0 = ((const float4*)(v + base))[lane * 2];
        const float4 v1 = ((const float4*)(v + base))[lane * 2 + 1];
        *(float4*)&sq[w][sh][sd]     = q0;
        *(float4*)&sq[w][sh][sd + 4] = q1;
        *(float4*)&sk[w][sh][sd]     = k0;
        *(float4*)&sk[w][sh][sd + 4] = k1;
        *(float4*)&sv[w][sh][sd]     = v0;
        *(float4*)&sv[w][sh][sd + 4] = v1;
    }
    __syncthreads();

    // scores: lane (n = lane>>3, h = lane&7) -> s[n][h] = q[n] . k[h]
    const int n  = lane >> 3;
    const int hh = lane & 7;
    float s = 0.f;
    #pragma unroll
    for (int d = 0; d < 64; d += 4) {
        const float4 a = *(const float4*)&sq[w][n][d];
        const float4 b = *(const float4*)&sk[w][hh][d];
        s += a.x * b.x + a.y * b.y + a.z * b.z + a.w * b.w;
    }
    // denom[n] = sum_h s[n][h]  (h-group = 8 consecutive lanes)
    float den = s;
    den += __shfl_xor(den, 1);
    den += __shfl_xor(den, 2);
    den += __shfl_xor(den, 4);
    const float p = s / den;

    // broadcast normalized scores of my n-group
    float pl[8];
    #pragma unroll
    for (int h = 0; h < 8; ++h) pl[h] = __shfl(p, (lane & 56) | h);

    // out[n][e] = sum_h pl[h] * v[h][e]; lane covers e = (lane&7)*8 .. +7
    const int eg = (lane & 7) * 8;
    float o[8] = {0.f, 0.f, 0.f, 0.f, 0.f, 0.f, 0.f, 0.f};
    #pragma unroll
    for (int h = 0; h < 8; ++h) {
        const float4 v0 = *(const float4*)&sv[w][h][eg];
        const float4 v1 = *(const float4*)&sv[w][h][eg + 4];
        o[0] += pl[h] * v0.x; o[1] += pl[h] * v0.y;
        o[2] += pl[h] * v0.z; o[3] += pl[h] * v0.w;
        o[4] += pl[h] * v1.x; o[5] += pl[h] * v1.y;
        o[6] += pl[h] * v1.z; o[7] += pl[h] * v1.w;
    }
    union { short8 s8; __hip_bfloat16 b[8]; } pk;
    #pragma unroll
    for (int j = 0; j < 8; ++j) pk.b[j] = __float2bfloat16(o[j]);
    *(short8*)(attn + base + (size_t)lane * 8) = pk.s8;   // contiguous 1KB/wave
}

// ---------------------------------------------------------------------------
// LayerNorm(h + fh)*gamma + beta — one wave per row, 4 rows/block, float4 IO.
// NOTE: fh aliases out (same-address read-then-write per thread) — no
// __restrict__ on those two.
// ---------------------------------------------------------------------------
__global__ __launch_bounds__(256) void ln_kernel(
    const float* __restrict__ h, const float* fh,
    const float* __restrict__ gamma, const float* __restrict__ beta,
    float* out)
{
    const int lane = threadIdx.x & 63;
    const int wave = threadIdx.x >> 6;
    const size_t base = ((size_t)blockIdx.x * 4 + wave) * DIM;

    const float4 a0 = ((const float4*)(h + base))[lane * 2];
    const float4 a1 = ((const float4*)(h + base))[lane * 2 + 1];
    const float4 b0 = ((const float4*)(fh + base))[lane * 2];
    const float4 b1 = ((const float4*)(fh + base))[lane * 2 + 1];

    float x[8];
    x[0] = a0.x + b0.x; x[1] = a0.y + b0.y; x[2] = a0.z + b0.z; x[3] = a0.w + b0.w;
    x[4] = a1.x + b1.x; x[5] = a1.y + b1.y; x[6] = a1.z + b1.z; x[7] = a1.w + b1.w;

    float s = 0.f;
    #pragma unroll
    for (int i = 0; i < 8; ++i) s += x[i];
    #pragma unroll
    for (int off = 32; off > 0; off >>= 1) s += __shfl_down(s, off);
    const float mu = __shfl(s, 0) * (1.f / DIM);

    float vs = 0.f;
    #pragma unroll
    for (int i = 0; i < 8; ++i) { const float d = x[i] - mu; vs += d * d; }
    #pragma unroll
    for (int off = 32; off > 0; off >>= 1) vs += __shfl_down(vs, off);
    const float rstd = rsqrtf(__shfl(vs, 0) * (1.f / DIM) + LN_EPS);

    const float4 g0 = ((const float4*)gamma)[lane * 2];
    const float4 g1 = ((const float4*)gamma)[lane * 2 + 1];
    const float4 e0 = ((const float4*)beta)[lane * 2];
    const float4 e1 = ((const float4*)beta)[lane * 2 + 1];

    float4 r0, r1;
    r0.x = (x[0] - mu) * rstd * g0.x + e0.x;
    r0.y = (x[1] - mu) * rstd * g0.y + e0.y;
    r0.z = (x[2] - mu) * rstd * g0.z + e0.z;
    r0.w = (x[3] - mu) * rstd * g0.w + e0.w;
    r1.x = (x[4] - mu) * rstd * g1.x + e1.x;
    r1.y = (x[5] - mu) * rstd * g1.y + e1.y;
    r1.z = (x[6] - mu) * rstd * g1.z + e1.z;
    r1.w = (x[7] - mu) * rstd * g1.w + e1.w;

    ((float4*)(out + base))[lane * 2]     = r0;
    ((float4*)(out + base))[lane * 2 + 1] = r1;
}

// ---------------------------------------------------------------------------
extern "C" void kernel_launch(void* const* d_in, const int* in_sizes, int n_in,
                              void* d_out, int out_size, void* d_ws, size_t ws_size,
                              hipStream_t stream)
{
    const float* h     = (const float*)d_in[0];
    const float* Wq    = (const float*)d_in[1];
    const float* Wk    = (const float*)d_in[2];
    const float* Wv    = (const float*)d_in[3];
    const float* Wf    = (const float*)d_in[4];
    const float* gamma = (const float*)d_in[5];
    const float* beta  = (const float*)d_in[6];

    const size_t ND = (size_t)NROWS * DIM;
    float* out = (float*)d_out;
    float* qo  = out + ND;
    float* ko  = out + 2 * ND;
    float* vo  = out + 3 * ND;
    float* fh  = out;                       // stage fh in out[0..ND) (dead until LN)

    __hip_bfloat16* hb  = (__hip_bfloat16*)d_ws;     // ND bf16 (32 MB)
    __hip_bfloat16* wt  = hb + ND;                   // 4 x 512x512 bf16, contiguous
    __hip_bfloat16* wtf = wt + 3 * DIM * DIM;        // Wf^T
    __hip_bfloat16* attnb = hb;                      // reuse hb (dead after QKV GEMM)

    hconv_kernel<<<NROWS * DIM / 1024, 256, 0, stream>>>(h, hb);
    wtrans_kernel<<<dim3(16, 16, 4), 256, 0, stream>>>(Wq, Wk, Wv, Wf, wt);

    // fused Q|K|V GEMM: Bt = 1536x512 concat, C panels qo/ko/vo (contiguous)
    mfma_gemm_kernel<<<dim3(12, NROWS / 128), 256, 0, stream>>>(hb, wt, qo, 1);

    attn_kernel<<<NROWS / 4, 256, 0, stream>>>(qo, ko, vo, attnb);

    mfma_gemm_kernel<<<dim3(4, NROWS / 128), 256, 0, stream>>>(attnb, wtf, fh, 0);

    ln_kernel<<<NROWS / 4, 256, 0, stream>>>(h, fh, gamma, beta, out);
}

// Round 2
// 442.300 us; speedup vs baseline: 1.2267x; 1.0525x over previous
//
#include <hip/hip_runtime.h>
#include <hip/hip_bf16.h>

#define NROWS 32768
#define DIM   512
#define HEADS 8
#define LN_EPS 1e-5f

typedef __attribute__((ext_vector_type(8))) short short8;   // 8 bf16 (4 VGPRs)
typedef __attribute__((ext_vector_type(4))) float floatx4;  // MFMA acc

typedef __attribute__((address_space(3))) void lds_void;
typedef __attribute__((address_space(1))) void gbl_void;

// async global->LDS, 16 B per lane; LDS dest = wave-uniform base + lane*16
__device__ __forceinline__ void async16(const void* g, void* l) {
    __builtin_amdgcn_global_load_lds(
        (gbl_void*)(unsigned long long)(uintptr_t)g,
        (lds_void*)(unsigned int)(uintptr_t)l,
        16, 0, 0);
}

// ---------------------------------------------------------------------------
// h (fp32) -> hb (bf16), vectorized
// ---------------------------------------------------------------------------
__global__ __launch_bounds__(256) void hconv_kernel(
    const float* __restrict__ h, __hip_bfloat16* __restrict__ hb)
{
    const size_t i = ((size_t)blockIdx.x * 256 + threadIdx.x) * 4;
    const float4 f = *(const float4*)(h + i);
    union { ushort4 u; __hip_bfloat16 b[4]; } pk;
    pk.b[0] = __float2bfloat16(f.x);
    pk.b[1] = __float2bfloat16(f.y);
    pk.b[2] = __float2bfloat16(f.z);
    pk.b[3] = __float2bfloat16(f.w);
    *(ushort4*)(hb + i) = pk.u;
}

// ---------------------------------------------------------------------------
// All four W [K=512][N=512] fp32 -> Wt [N][K] bf16, one launch (blockIdx.z).
// wtq/wtk/wtv land contiguous -> QKV GEMM sees one 1536x512 Bt.
// ---------------------------------------------------------------------------
__global__ __launch_bounds__(256) void wtrans_kernel(
    const float* __restrict__ Wq, const float* __restrict__ Wk,
    const float* __restrict__ Wv, const float* __restrict__ Wf,
    __hip_bfloat16* __restrict__ Wt)
{
    __shared__ float tile[32][33];
    const int z = blockIdx.z;
    const float* W = (z == 0) ? Wq : (z == 1) ? Wk : (z == 2) ? Wv : Wf;
    __hip_bfloat16* dst = Wt + (size_t)z * DIM * DIM;

    const int bn = blockIdx.x * 32;   // n block
    const int bk = blockIdx.y * 32;   // k block
    const int tx = threadIdx.x & 31;
    const int ty = threadIdx.x >> 5;  // 0..7
    #pragma unroll
    for (int i = ty; i < 32; i += 8)
        tile[i][tx] = W[(size_t)(bk + i) * DIM + bn + tx];
    __syncthreads();
    #pragma unroll
    for (int i = ty; i < 32; i += 8)
        dst[(size_t)(bn + i) * DIM + bk + tx] = __float2bfloat16(tile[tx][i]);
}

// ---------------------------------------------------------------------------
// MFMA GEMM: C[M,*] fp32 = A[M,512](bf16) @ Bt[n][k](bf16)^T.
// 128x128 tile, BK=32, 16 K-tiles, 256 thr = 4 waves (2x2), 4x4 frags/wave.
// Double-buffered LDS (2 x 16 KB) + counted vmcnt + raw barriers:
//   prologue: stage(tile0)
//   iter t:   stage(t+1) -> [vmcnt(4); s_barrier] -> ds_read+16 MFMA ->
//             [s_barrier]      (releases buf t&1 for stage t+2)
// vmcnt completes in order [m135]: vmcnt(4) == "tile t's 4 loads landed",
// tile t+1's 4 stay in flight across the barrier (T4). Waits are single
// asm volatile + "memory" clobber => no LDS/global op crosses them.
// LDS chunk swizzle (verified r0): phys chunk p stores logical (r = p>>2,
// kq = (p&3) ^ ((r>>1)&3)); frag ds_read_b128 then 2-way/bank = free [m136].
// qkv mode: Bt = 1536-row concat; C panel = bx>>2, col = (bx&3)*128,
// relu on q,k panels only.  XCD-swizzled grid (nwg % 8 == 0 for both calls).
// ---------------------------------------------------------------------------
__global__ __launch_bounds__(256) void mfma_gemm_kernel(
    const __hip_bfloat16* __restrict__ A,
    const __hip_bfloat16* __restrict__ Bt,
    float* __restrict__ C, int qkv)
{
    __shared__ __align__(16) char smem[32768];   // buf0: A|B 8K|8K, buf1 same

    const int t    = threadIdx.x;
    const int lane = t & 63;
    const int w    = t >> 6;
    const int wm   = w >> 1, wn = w & 1;
    const int l16  = lane & 15, quad = lane >> 4;

    // T1: XCD-aware block swizzle (consecutive logical ids on one XCD)
    const int nwg  = gridDim.x * gridDim.y;
    int flat = blockIdx.y * gridDim.x + blockIdx.x;
    flat = (flat & 7) * (nwg >> 3) + (flat >> 3);
    const int bx = flat % gridDim.x;
    const int by = flat / gridDim.x;

    const int bm = by * 128;
    const int bn = bx * 128;            // Bt row panel (global across concat)

    float* Cp;
    int ccol, relu;
    if (qkv) {
        Cp   = C + (size_t)(bx >> 2) * ((size_t)NROWS * DIM);
        ccol = (bx & 3) * 128;
        relu = (bx >> 2) < 2;
    } else {
        Cp = C; ccol = bn; relu = 0;
    }

    // staging: per BK=32 tile, 512 chunks(16B)/operand; wave w covers
    // physical chunks c0 = w*128+lane and c1 = c0+64.
    const int c0 = w * 128 + lane;
    const int c1 = c0 + 64;
    const int r0 = c0 >> 2, kq0 = (c0 & 3) ^ ((r0 >> 1) & 3);
    const int r1 = c1 >> 2, kq1 = (c1 & 3) ^ ((r1 >> 1) & 3);

    const int offA0 = (bm + r0) * DIM + kq0 * 8;
    const int offA1 = (bm + r1) * DIM + kq1 * 8;
    const int offB0 = (bn + r0) * DIM + kq0 * 8;
    const int offB1 = (bn + r1) * DIM + kq1 * 8;
    const int ldsC0 = (w * 128) * 16;          // wave-uniform LDS chunk bases
    const int ldsC1 = (w * 128 + 64) * 16;

    // loop-invariant frag LDS byte offsets (relative to buffer base)
    int aoff[4], boff[4];
    #pragma unroll
    for (int i = 0; i < 4; ++i) {
        const int ra = wm * 64 + i * 16 + l16;
        aoff[i] = (ra * 4 + (quad ^ ((ra >> 1) & 3))) * 16;
        const int rb = wn * 64 + i * 16 + l16;
        boff[i] = 8192 + (rb * 4 + (quad ^ ((rb >> 1) & 3))) * 16;
    }

    floatx4 acc[4][4];
    #pragma unroll
    for (int i = 0; i < 4; ++i)
        #pragma unroll
        for (int j = 0; j < 4; ++j)
            acc[i][j] = (floatx4){0.f, 0.f, 0.f, 0.f};

    // stage tile tt (4 async16 per wave) into buffer tt&1
    #define STAGE(tt) do {                                                  \
        char* _b = smem + ((tt) & 1) * 16384;                               \
        const int _k0 = (tt) * 32;                                          \
        async16(A  + offA0 + _k0, _b + ldsC0);                              \
        async16(A  + offA1 + _k0, _b + ldsC1);                              \
        async16(Bt + offB0 + _k0, _b + 8192 + ldsC0);                       \
        async16(Bt + offB1 + _k0, _b + 8192 + ldsC1);                       \
    } while (0)

    #define COMPUTE(tt) do {                                                \
        const char* _b = smem + ((tt) & 1) * 16384;                         \
        short8 af[4], bf[4];                                                \
        _Pragma("unroll")                                                   \
        for (int i = 0; i < 4; ++i) af[i] = *(const short8*)(_b + aoff[i]); \
        _Pragma("unroll")                                                   \
        for (int j = 0; j < 4; ++j) bf[j] = *(const short8*)(_b + boff[j]); \
        _Pragma("unroll")                                                   \
        for (int i = 0; i < 4; ++i)                                         \
            _Pragma("unroll")                                               \
            for (int j = 0; j < 4; ++j)                                     \
                acc[i][j] = __builtin_amdgcn_mfma_f32_16x16x32_bf16(        \
                    af[i], bf[j], acc[i][j], 0, 0, 0);                      \
    } while (0)

    STAGE(0);
    for (int kt = 0; kt < 15; ++kt) {
        STAGE(kt + 1);
        // tile kt's 4 loads done; kt+1's 4 stay in flight across barrier
        asm volatile("s_waitcnt vmcnt(4)\n\ts_barrier" ::: "memory");
        COMPUTE(kt);
        asm volatile("s_barrier" ::: "memory");   // release buf kt&1
    }
    asm volatile("s_waitcnt vmcnt(0)\n\ts_barrier" ::: "memory");
    COMPUTE(15);

    #undef STAGE
    #undef COMPUTE

    // epilogue: D row = quad*4 + reg, col = lane&15  [m89]
    #pragma unroll
    for (int i = 0; i < 4; ++i) {
        const int gr = bm + wm * 64 + i * 16 + quad * 4;
        #pragma unroll
        for (int j = 0; j < 4; ++j) {
            const int gc = ccol + wn * 64 + j * 16 + l16;
            #pragma unroll
            for (int rg = 0; rg < 4; ++rg) {
                float vv = acc[i][j][rg];
                if (relu) vv = fmaxf(vv, 0.f);
                Cp[(size_t)(gr + rg) * DIM + gc] = vv;
            }
        }
    }
}

// ---------------------------------------------------------------------------
// Linear attention, S-form:  num = (q k^T) v,  denom = rowsum(q k^T).
// Per row: S is only 8x8 (H=8) -> 16 KFLOP/row vs 131 K for the kv-form.
// One wave per row, 4 rows/block. Single barrier; P broadcast via shfl.
// Writes attn directly as bf16 (input to the Wf GEMM).
// ---------------------------------------------------------------------------
__global__ __launch_bounds__(256) void attn_kernel(
    const float* __restrict__ q, const float* __restrict__ k,
    const float* __restrict__ v, __hip_bfloat16* __restrict__ attn)
{
    __shared__ float sq[4][8][68];   // [wave][head][64, pad 68 keeps 16B align]
    __shared__ float sk[4][8][68];
    __shared__ float sv[4][8][68];

    const int t = threadIdx.x;
    const int w = t >> 6, lane = t & 63;
    const size_t base = ((size_t)blockIdx.x * 4 + w) * DIM;

    // stage one row of q,k,v: lane covers 8 floats (head sh, offset sd)
    const int sh = lane >> 3;
    const int sd = (lane & 7) * 8;
    {
        const float4 q0 = ((const float4*)(q + base))[lane * 2];
        const float4 q1 = ((const float4*)(q + base))[lane * 2 + 1];
        const float4 k0 = ((const float4*)(k + base))[lane * 2];
        const float4 k1 = ((const float4*)(k + base))[lane * 2 + 1];
        const float4 v0 = ((const float4*)(v + base))[lane * 2];
        const float4 v1 = ((const float4*)(v + base))[lane * 2 + 1];
        *(float4*)&sq[w][sh][sd]     = q0;
        *(float4*)&sq[w][sh][sd + 4] = q1;
        *(float4*)&sk[w][sh][sd]     = k0;
        *(float4*)&sk[w][sh][sd + 4] = k1;
        *(float4*)&sv[w][sh][sd]     = v0;
        *(float4*)&sv[w][sh][sd + 4] = v1;
    }
    __syncthreads();

    // scores: lane (n = lane>>3, h = lane&7) -> s[n][h] = q[n] . k[h]
    const int n  = lane >> 3;
    const int hh = lane & 7;
    float s = 0.f;
    #pragma unroll
    for (int d = 0; d < 64; d += 4) {
        const float4 a = *(const float4*)&sq[w][n][d];
        const float4 b = *(const float4*)&sk[w][hh][d];
        s += a.x * b.x + a.y * b.y + a.z * b.z + a.w * b.w;
    }
    // denom[n] = sum_h s[n][h]  (h-group = 8 consecutive lanes)
    float den = s;
    den += __shfl_xor(den, 1);
    den += __shfl_xor(den, 2);
    den += __shfl_xor(den, 4);
    const float p = s / den;

    // broadcast normalized scores of my n-group
    float pl[8];
    #pragma unroll
    for (int h = 0; h < 8; ++h) pl[h] = __shfl(p, (lane & 56) | h);

    // out[n][e] = sum_h pl[h] * v[h][e]; lane covers e = (lane&7)*8 .. +7
    const int eg = (lane & 7) * 8;
    float o[8] = {0.f, 0.f, 0.f, 0.f, 0.f, 0.f, 0.f, 0.f};
    #pragma unroll
    for (int h = 0; h < 8; ++h) {
        const float4 v0 = *(const float4*)&sv[w][h][eg];
        const float4 v1 = *(const float4*)&sv[w][h][eg + 4];
        o[0] += pl[h] * v0.x; o[1] += pl[h] * v0.y;
        o[2] += pl[h] * v0.z; o[3] += pl[h] * v0.w;
        o[4] += pl[h] * v1.x; o[5] += pl[h] * v1.y;
        o[6] += pl[h] * v1.z; o[7] += pl[h] * v1.w;
    }
    union { short8 s8; __hip_bfloat16 b[8]; } pk;
    #pragma unroll
    for (int j = 0; j < 8; ++j) pk.b[j] = __float2bfloat16(o[j]);
    *(short8*)(attn + base + (size_t)lane * 8) = pk.s8;   // contiguous 1KB/wave
}

// ---------------------------------------------------------------------------
// LayerNorm(h + fh)*gamma + beta — one wave per row, 4 rows/block, float4 IO.
// NOTE: fh aliases out (same-address read-then-write per thread) — no
// __restrict__ on those two.
// ---------------------------------------------------------------------------
__global__ __launch_bounds__(256) void ln_kernel(
    const float* __restrict__ h, const float* fh,
    const float* __restrict__ gamma, const float* __restrict__ beta,
    float* out)
{
    const int lane = threadIdx.x & 63;
    const int wave = threadIdx.x >> 6;
    const size_t base = ((size_t)blockIdx.x * 4 + wave) * DIM;

    const float4 a0 = ((const float4*)(h + base))[lane * 2];
    const float4 a1 = ((const float4*)(h + base))[lane * 2 + 1];
    const float4 b0 = ((const float4*)(fh + base))[lane * 2];
    const float4 b1 = ((const float4*)(fh + base))[lane * 2 + 1];

    float x[8];
    x[0] = a0.x + b0.x; x[1] = a0.y + b0.y; x[2] = a0.z + b0.z; x[3] = a0.w + b0.w;
    x[4] = a1.x + b1.x; x[5] = a1.y + b1.y; x[6] = a1.z + b1.z; x[7] = a1.w + b1.w;

    float s = 0.f;
    #pragma unroll
    for (int i = 0; i < 8; ++i) s += x[i];
    #pragma unroll
    for (int off = 32; off > 0; off >>= 1) s += __shfl_down(s, off);
    const float mu = __shfl(s, 0) * (1.f / DIM);

    float vs = 0.f;
    #pragma unroll
    for (int i = 0; i < 8; ++i) { const float d = x[i] - mu; vs += d * d; }
    #pragma unroll
    for (int off = 32; off > 0; off >>= 1) vs += __shfl_down(vs, off);
    const float rstd = rsqrtf(__shfl(vs, 0) * (1.f / DIM) + LN_EPS);

    const float4 g0 = ((const float4*)gamma)[lane * 2];
    const float4 g1 = ((const float4*)gamma)[lane * 2 + 1];
    const float4 e0 = ((const float4*)beta)[lane * 2];
    const float4 e1 = ((const float4*)beta)[lane * 2 + 1];

    float4 r0, r1;
    r0.x = (x[0] - mu) * rstd * g0.x + e0.x;
    r0.y = (x[1] - mu) * rstd * g0.y + e0.y;
    r0.z = (x[2] - mu) * rstd * g0.z + e0.z;
    r0.w = (x[3] - mu) * rstd * g0.w + e0.w;
    r1.x = (x[4] - mu) * rstd * g1.x + e1.x;
    r1.y = (x[5] - mu) * rstd * g1.y + e1.y;
    r1.z = (x[6] - mu) * rstd * g1.z + e1.z;
    r1.w = (x[7] - mu) * rstd * g1.w + e1.w;

    ((float4*)(out + base))[lane * 2]     = r0;
    ((float4*)(out + base))[lane * 2 + 1] = r1;
}

// ---------------------------------------------------------------------------
extern "C" void kernel_launch(void* const* d_in, const int* in_sizes, int n_in,
                              void* d_out, int out_size, void* d_ws, size_t ws_size,
                              hipStream_t stream)
{
    const float* h     = (const float*)d_in[0];
    const float* Wq    = (const float*)d_in[1];
    const float* Wk    = (const float*)d_in[2];
    const float* Wv    = (const float*)d_in[3];
    const float* Wf    = (const float*)d_in[4];
    const float* gamma = (const float*)d_in[5];
    const float* beta  = (const float*)d_in[6];

    const size_t ND = (size_t)NROWS * DIM;
    float* out = (float*)d_out;
    float* qo  = out + ND;
    float* ko  = out + 2 * ND;
    float* vo  = out + 3 * ND;
    float* fh  = out;                       // stage fh in out[0..ND) (dead until LN)

    __hip_bfloat16* hb  = (__hip_bfloat16*)d_ws;     // ND bf16 (32 MB)
    __hip_bfloat16* wt  = hb + ND;                   // 4 x 512x512 bf16, contiguous
    __hip_bfloat16* wtf = wt + 3 * DIM * DIM;        // Wf^T
    __hip_bfloat16* attnb = hb;                      // reuse hb (dead after QKV GEMM)

    hconv_kernel<<<NROWS * DIM / 1024, 256, 0, stream>>>(h, hb);
    wtrans_kernel<<<dim3(16, 16, 4), 256, 0, stream>>>(Wq, Wk, Wv, Wf, wt);

    // fused Q|K|V GEMM: Bt = 1536x512 concat, C panels qo/ko/vo (contiguous)
    mfma_gemm_kernel<<<dim3(12, NROWS / 128), 256, 0, stream>>>(hb, wt, qo, 1);

    attn_kernel<<<NROWS / 4, 256, 0, stream>>>(qo, ko, vo, attnb);

    mfma_gemm_kernel<<<dim3(4, NROWS / 128), 256, 0, stream>>>(attnb, wtf, fh, 0);

    ln_kernel<<<NROWS / 4, 256, 0, stream>>>(h, fh, gamma, beta, out);
}

// Round 3
// 440.794 us; speedup vs baseline: 1.2309x; 1.0034x over previous
//
#include <hip/hip_runtime.h>
#include <hip/hip_bf16.h>

#define NROWS 32768
#define DIM   512
#define HEADS 8
#define LN_EPS 1e-5f

typedef __attribute__((ext_vector_type(8))) short short8;   // 8 bf16 (4 VGPRs)
typedef __attribute__((ext_vector_type(4))) float floatx4;  // MFMA acc

typedef __attribute__((address_space(3))) void lds_void;
typedef __attribute__((address_space(1))) void gbl_void;

// async global->LDS, 16 B per lane; LDS dest = wave-uniform base + lane*16
__device__ __forceinline__ void async16(const void* g, void* l) {
    __builtin_amdgcn_global_load_lds(
        (gbl_void*)(unsigned long long)(uintptr_t)g,
        (lds_void*)(unsigned int)(uintptr_t)l,
        16, 0, 0);
}

// ---------------------------------------------------------------------------
// h (fp32) -> hb (bf16), vectorized
// ---------------------------------------------------------------------------
__global__ __launch_bounds__(256) void hconv_kernel(
    const float* __restrict__ h, __hip_bfloat16* __restrict__ hb)
{
    const size_t i = ((size_t)blockIdx.x * 256 + threadIdx.x) * 4;
    const float4 f = *(const float4*)(h + i);
    union { ushort4 u; __hip_bfloat16 b[4]; } pk;
    pk.b[0] = __float2bfloat16(f.x);
    pk.b[1] = __float2bfloat16(f.y);
    pk.b[2] = __float2bfloat16(f.z);
    pk.b[3] = __float2bfloat16(f.w);
    *(ushort4*)(hb + i) = pk.u;
}

// ---------------------------------------------------------------------------
// All four W [K=512][N=512] fp32 -> Wt [N][K] bf16, one launch (blockIdx.z).
// wtq/wtk/wtv land contiguous -> QKV GEMM sees one 1536x512 Bt.
// ---------------------------------------------------------------------------
__global__ __launch_bounds__(256) void wtrans_kernel(
    const float* __restrict__ Wq, const float* __restrict__ Wk,
    const float* __restrict__ Wv, const float* __restrict__ Wf,
    __hip_bfloat16* __restrict__ Wt)
{
    __shared__ float tile[32][33];
    const int z = blockIdx.z;
    const float* W = (z == 0) ? Wq : (z == 1) ? Wk : (z == 2) ? Wv : Wf;
    __hip_bfloat16* dst = Wt + (size_t)z * DIM * DIM;

    const int bn = blockIdx.x * 32;   // n block
    const int bk = blockIdx.y * 32;   // k block
    const int tx = threadIdx.x & 31;
    const int ty = threadIdx.x >> 5;  // 0..7
    #pragma unroll
    for (int i = ty; i < 32; i += 8)
        tile[i][tx] = W[(size_t)(bk + i) * DIM + bn + tx];
    __syncthreads();
    #pragma unroll
    for (int i = ty; i < 32; i += 8)
        dst[(size_t)(bn + i) * DIM + bk + tx] = __float2bfloat16(tile[tx][i]);
}

// ---------------------------------------------------------------------------
// MFMA GEMM: C[M,*] fp32 = A[M,512](bf16) @ Bt[n][k](bf16)^T.
// Block tile 256x128 (MxN), 4 waves (2x2), WAVE TILE 128x64 (8x4 frags of
// 16x16x32, 128-AGPR acc) -> 12 KB LDS frags per 32 MFMA per wave (1.33x
// better FLOP/LDS-byte than 64x64) and half the blocks/epilogues.
// BK=32, 16 K-tiles, double-buffered LDS 2 x (A 16K | B 8K) = 48 KB.
// Pipeline (protocol verified r2): STAGE(t+1) -> [vmcnt(6); s_barrier]
// -> ds_read+32 MFMA -> [s_barrier]. vmcnt completes in order [m135]:
// vmcnt(6) == tile t's 6 loads landed; t+1's stay in flight (T4).
// LDS chunk swizzle (verified r0): phys chunk p holds logical (r = p>>2,
// kq = (p&3) ^ ((r>>1)&3)); frag ds_read_b128 is 2-way/bank = free [m136].
// qkv mode: Bt = 1536-row concat; C panel = bx>>2, col = (bx&3)*128,
// relu on q,k panels. XCD-swizzled grid (nwg % 8 == 0 both calls) -> each
// XCD owns a 4 MB A slab = exactly its L2.
// ---------------------------------------------------------------------------
__global__ __launch_bounds__(256, 2) void mfma_gemm_kernel(
    const __hip_bfloat16* __restrict__ A,
    const __hip_bfloat16* __restrict__ Bt,
    float* __restrict__ C, int qkv)
{
    __shared__ __align__(16) char smem[49152];   // buf: A 16K | B 8K, x2

    const int t    = threadIdx.x;
    const int lane = t & 63;
    const int w    = t >> 6;
    const int wm   = w >> 1, wn = w & 1;
    const int l16  = lane & 15, quad = lane >> 4;

    // T1: XCD-aware block swizzle (consecutive logical ids on one XCD)
    const int nwg  = gridDim.x * gridDim.y;
    int flat = blockIdx.y * gridDim.x + blockIdx.x;
    flat = (flat & 7) * (nwg >> 3) + (flat >> 3);
    const int bx = flat % gridDim.x;
    const int by = flat / gridDim.x;

    const int bm = by * 256;
    const int bn = bx * 128;            // Bt row panel (global across concat)

    float* Cp;
    int ccol, relu;
    if (qkv) {
        Cp   = C + (size_t)(bx >> 2) * ((size_t)NROWS * DIM);
        ccol = (bx & 3) * 128;
        relu = (bx >> 2) < 2;
    } else {
        Cp = C; ccol = bn; relu = 0;
    }

    // staging: per BK=32 tile, A = 1024 chunks(16B) (256 rows x 4),
    // B = 512 chunks (128 rows x 4). Wave w: A chunks [w*256, w*256+256),
    // B chunks [w*128, w*128+128). 6 async16 per wave per tile.
    int offA[4], offB[2];
    int ldsA[4], ldsB[2];
    #pragma unroll
    for (int s = 0; s < 4; ++s) {
        const int p = w * 256 + s * 64 + lane;
        const int r = p >> 2, kq = (p & 3) ^ ((r >> 1) & 3);
        offA[s] = (bm + r) * DIM + kq * 8;
        ldsA[s] = (w * 256 + s * 64) * 16;          // wave-uniform base
    }
    #pragma unroll
    for (int s = 0; s < 2; ++s) {
        const int p = w * 128 + s * 64 + lane;
        const int r = p >> 2, kq = (p & 3) ^ ((r >> 1) & 3);
        offB[s] = (bn + r) * DIM + kq * 8;
        ldsB[s] = 16384 + (w * 128 + s * 64) * 16;  // wave-uniform base
    }

    // loop-invariant frag LDS byte offsets (relative to buffer base)
    int aoff[8], boff[4];
    #pragma unroll
    for (int i = 0; i < 8; ++i) {
        const int ra = wm * 128 + i * 16 + l16;
        aoff[i] = (ra * 4 + (quad ^ ((ra >> 1) & 3))) * 16;
    }
    #pragma unroll
    for (int j = 0; j < 4; ++j) {
        const int rb = wn * 64 + j * 16 + l16;
        boff[j] = 16384 + (rb * 4 + (quad ^ ((rb >> 1) & 3))) * 16;
    }

    floatx4 acc[8][4];
    #pragma unroll
    for (int i = 0; i < 8; ++i)
        #pragma unroll
        for (int j = 0; j < 4; ++j)
            acc[i][j] = (floatx4){0.f, 0.f, 0.f, 0.f};

    // stage tile tt (6 async16 per wave) into buffer tt&1
    #define STAGE(tt) do {                                                  \
        char* _b = smem + ((tt) & 1) * 24576;                               \
        const int _k0 = (tt) * 32;                                          \
        async16(A  + offA[0] + _k0, _b + ldsA[0]);                          \
        async16(A  + offA[1] + _k0, _b + ldsA[1]);                          \
        async16(A  + offA[2] + _k0, _b + ldsA[2]);                          \
        async16(A  + offA[3] + _k0, _b + ldsA[3]);                          \
        async16(Bt + offB[0] + _k0, _b + ldsB[0]);                          \
        async16(Bt + offB[1] + _k0, _b + ldsB[1]);                          \
    } while (0)

    #define COMPUTE(tt) do {                                                \
        const char* _b = smem + ((tt) & 1) * 24576;                         \
        short8 af[8], bf[4];                                                \
        _Pragma("unroll")                                                   \
        for (int i = 0; i < 8; ++i) af[i] = *(const short8*)(_b + aoff[i]); \
        _Pragma("unroll")                                                   \
        for (int j = 0; j < 4; ++j) bf[j] = *(const short8*)(_b + boff[j]); \
        _Pragma("unroll")                                                   \
        for (int i = 0; i < 8; ++i)                                         \
            _Pragma("unroll")                                               \
            for (int j = 0; j < 4; ++j)                                     \
                acc[i][j] = __builtin_amdgcn_mfma_f32_16x16x32_bf16(        \
                    af[i], bf[j], acc[i][j], 0, 0, 0);                      \
    } while (0)

    STAGE(0);
    for (int kt = 0; kt < 15; ++kt) {
        STAGE(kt + 1);
        // tile kt's 6 loads done; kt+1's 6 stay in flight across barrier
        asm volatile("s_waitcnt vmcnt(6)\n\ts_barrier" ::: "memory");
        COMPUTE(kt);
        asm volatile("s_barrier" ::: "memory");   // release buf kt&1
    }
    asm volatile("s_waitcnt vmcnt(0)\n\ts_barrier" ::: "memory");
    COMPUTE(15);

    #undef STAGE
    #undef COMPUTE

    // epilogue: D row = quad*4 + reg, col = lane&15  [m89]
    #pragma unroll
    for (int i = 0; i < 8; ++i) {
        const int gr = bm + wm * 128 + i * 16 + quad * 4;
        #pragma unroll
        for (int j = 0; j < 4; ++j) {
            const int gc = ccol + wn * 64 + j * 16 + l16;
            #pragma unroll
            for (int rg = 0; rg < 4; ++rg) {
                float vv = acc[i][j][rg];
                if (relu) vv = fmaxf(vv, 0.f);
                Cp[(size_t)(gr + rg) * DIM + gc] = vv;
            }
        }
    }
}

// ---------------------------------------------------------------------------
// Linear attention, S-form:  num = (q k^T) v,  denom = rowsum(q k^T).
// Per row: S is only 8x8 (H=8) -> 16 KFLOP/row vs 131 K for the kv-form.
// One wave per row, 4 rows/block. Single barrier; P broadcast via shfl.
// Writes attn directly as bf16 (input to the Wf GEMM).
// ---------------------------------------------------------------------------
__global__ __launch_bounds__(256) void attn_kernel(
    const float* __restrict__ q, const float* __restrict__ k,
    const float* __restrict__ v, __hip_bfloat16* __restrict__ attn)
{
    __shared__ float sq[4][8][68];   // [wave][head][64, pad 68 keeps 16B align]
    __shared__ float sk[4][8][68];
    __shared__ float sv[4][8][68];

    const int t = threadIdx.x;
    const int w = t >> 6, lane = t & 63;
    const size_t base = ((size_t)blockIdx.x * 4 + w) * DIM;

    // stage one row of q,k,v: lane covers 8 floats (head sh, offset sd)
    const int sh = lane >> 3;
    const int sd = (lane & 7) * 8;
    {
        const float4 q0 = ((const float4*)(q + base))[lane * 2];
        const float4 q1 = ((const float4*)(q + base))[lane * 2 + 1];
        const float4 k0 = ((const float4*)(k + base))[lane * 2];
        const float4 k1 = ((const float4*)(k + base))[lane * 2 + 1];
        const float4 v0 = ((const float4*)(v + base))[lane * 2];
        const float4 v1 = ((const float4*)(v + base))[lane * 2 + 1];
        *(float4*)&sq[w][sh][sd]     = q0;
        *(float4*)&sq[w][sh][sd + 4] = q1;
        *(float4*)&sk[w][sh][sd]     = k0;
        *(float4*)&sk[w][sh][sd + 4] = k1;
        *(float4*)&sv[w][sh][sd]     = v0;
        *(float4*)&sv[w][sh][sd + 4] = v1;
    }
    __syncthreads();

    // scores: lane (n = lane>>3, h = lane&7) -> s[n][h] = q[n] . k[h]
    const int n  = lane >> 3;
    const int hh = lane & 7;
    float s = 0.f;
    #pragma unroll
    for (int d = 0; d < 64; d += 4) {
        const float4 a = *(const float4*)&sq[w][n][d];
        const float4 b = *(const float4*)&sk[w][hh][d];
        s += a.x * b.x + a.y * b.y + a.z * b.z + a.w * b.w;
    }
    // denom[n] = sum_h s[n][h]  (h-group = 8 consecutive lanes)
    float den = s;
    den += __shfl_xor(den, 1);
    den += __shfl_xor(den, 2);
    den += __shfl_xor(den, 4);
    const float p = s / den;

    // broadcast normalized scores of my n-group
    float pl[8];
    #pragma unroll
    for (int h = 0; h < 8; ++h) pl[h] = __shfl(p, (lane & 56) | h);

    // out[n][e] = sum_h pl[h] * v[h][e]; lane covers e = (lane&7)*8 .. +7
    const int eg = (lane & 7) * 8;
    float o[8] = {0.f, 0.f, 0.f, 0.f, 0.f, 0.f, 0.f, 0.f};
    #pragma unroll
    for (int h = 0; h < 8; ++h) {
        const float4 v0 = *(const float4*)&sv[w][h][eg];
        const float4 v1 = *(const float4*)&sv[w][h][eg + 4];
        o[0] += pl[h] * v0.x; o[1] += pl[h] * v0.y;
        o[2] += pl[h] * v0.z; o[3] += pl[h] * v0.w;
        o[4] += pl[h] * v1.x; o[5] += pl[h] * v1.y;
        o[6] += pl[h] * v1.z; o[7] += pl[h] * v1.w;
    }
    union { short8 s8; __hip_bfloat16 b[8]; } pk;
    #pragma unroll
    for (int j = 0; j < 8; ++j) pk.b[j] = __float2bfloat16(o[j]);
    *(short8*)(attn + base + (size_t)lane * 8) = pk.s8;   // contiguous 1KB/wave
}

// ---------------------------------------------------------------------------
// LayerNorm(h + fh)*gamma + beta — one wave per row, 4 rows/block, float4 IO.
// NOTE: fh aliases out (same-address read-then-write per thread) — no
// __restrict__ on those two.
// ---------------------------------------------------------------------------
__global__ __launch_bounds__(256) void ln_kernel(
    const float* __restrict__ h, const float* fh,
    const float* __restrict__ gamma, const float* __restrict__ beta,
    float* out)
{
    const int lane = threadIdx.x & 63;
    const int wave = threadIdx.x >> 6;
    const size_t base = ((size_t)blockIdx.x * 4 + wave) * DIM;

    const float4 a0 = ((const float4*)(h + base))[lane * 2];
    const float4 a1 = ((const float4*)(h + base))[lane * 2 + 1];
    const float4 b0 = ((const float4*)(fh + base))[lane * 2];
    const float4 b1 = ((const float4*)(fh + base))[lane * 2 + 1];

    float x[8];
    x[0] = a0.x + b0.x; x[1] = a0.y + b0.y; x[2] = a0.z + b0.z; x[3] = a0.w + b0.w;
    x[4] = a1.x + b1.x; x[5] = a1.y + b1.y; x[6] = a1.z + b1.z; x[7] = a1.w + b1.w;

    float s = 0.f;
    #pragma unroll
    for (int i = 0; i < 8; ++i) s += x[i];
    #pragma unroll
    for (int off = 32; off > 0; off >>= 1) s += __shfl_down(s, off);
    const float mu = __shfl(s, 0) * (1.f / DIM);

    float vs = 0.f;
    #pragma unroll
    for (int i = 0; i < 8; ++i) { const float d = x[i] - mu; vs += d * d; }
    #pragma unroll
    for (int off = 32; off > 0; off >>= 1) vs += __shfl_down(vs, off);
    const float rstd = rsqrtf(__shfl(vs, 0) * (1.f / DIM) + LN_EPS);

    const float4 g0 = ((const float4*)gamma)[lane * 2];
    const float4 g1 = ((const float4*)gamma)[lane * 2 + 1];
    const float4 e0 = ((const float4*)beta)[lane * 2];
    const float4 e1 = ((const float4*)beta)[lane * 2 + 1];

    float4 r0, r1;
    r0.x = (x[0] - mu) * rstd * g0.x + e0.x;
    r0.y = (x[1] - mu) * rstd * g0.y + e0.y;
    r0.z = (x[2] - mu) * rstd * g0.z + e0.z;
    r0.w = (x[3] - mu) * rstd * g0.w + e0.w;
    r1.x = (x[4] - mu) * rstd * g1.x + e1.x;
    r1.y = (x[5] - mu) * rstd * g1.y + e1.y;
    r1.z = (x[6] - mu) * rstd * g1.z + e1.z;
    r1.w = (x[7] - mu) * rstd * g1.w + e1.w;

    ((float4*)(out + base))[lane * 2]     = r0;
    ((float4*)(out + base))[lane * 2 + 1] = r1;
}

// ---------------------------------------------------------------------------
extern "C" void kernel_launch(void* const* d_in, const int* in_sizes, int n_in,
                              void* d_out, int out_size, void* d_ws, size_t ws_size,
                              hipStream_t stream)
{
    const float* h     = (const float*)d_in[0];
    const float* Wq    = (const float*)d_in[1];
    const float* Wk    = (const float*)d_in[2];
    const float* Wv    = (const float*)d_in[3];
    const float* Wf    = (const float*)d_in[4];
    const float* gamma = (const float*)d_in[5];
    const float* beta  = (const float*)d_in[6];

    const size_t ND = (size_t)NROWS * DIM;
    float* out = (float*)d_out;
    float* qo  = out + ND;
    float* ko  = out + 2 * ND;
    float* vo  = out + 3 * ND;
    float* fh  = out;                       // stage fh in out[0..ND) (dead until LN)

    __hip_bfloat16* hb  = (__hip_bfloat16*)d_ws;     // ND bf16 (32 MB)
    __hip_bfloat16* wt  = hb + ND;                   // 4 x 512x512 bf16, contiguous
    __hip_bfloat16* wtf = wt + 3 * DIM * DIM;        // Wf^T
    __hip_bfloat16* attnb = hb;                      // reuse hb (dead after QKV GEMM)

    hconv_kernel<<<NROWS * DIM / 1024, 256, 0, stream>>>(h, hb);
    wtrans_kernel<<<dim3(16, 16, 4), 256, 0, stream>>>(Wq, Wk, Wv, Wf, wt);

    // fused Q|K|V GEMM: Bt = 1536x512 concat, C panels qo/ko/vo (contiguous)
    mfma_gemm_kernel<<<dim3(12, NROWS / 256), 256, 0, stream>>>(hb, wt, qo, 1);

    attn_kernel<<<NROWS / 4, 256, 0, stream>>>(qo, ko, vo, attnb);

    mfma_gemm_kernel<<<dim3(4, NROWS / 256), 256, 0, stream>>>(attnb, wtf, fh, 0);

    ln_kernel<<<NROWS / 4, 256, 0, stream>>>(h, fh, gamma, beta, out);
}